// Round 4
// baseline (731.871 us; speedup 1.0000x reference)
//
#include <hip/hip_runtime.h>

// GIN_MLP: 2x GIN conv (N=100000, E=1.6M, H=128) + per-batch context MLP (B=4096).
// Device-built dst-CSR -> fused aggregate+GEMM -> per-batch MLP. All f32.
// R4: stage-1 is a flat 8-deep gather pipeline (8 independent float4 gathers in
// flight before any consume; row boundaries handled in the consume loop), and
// the CSR scatter uses ranks recorded during hist (no scatter atomics).

#define CONV_NPB 32

__global__ void prep_transpose(const float* __restrict__ W1, const float* __restrict__ W2,
                               const float* __restrict__ Wc1, const float* __restrict__ Wc2,
                               float* __restrict__ Wt1, float* __restrict__ Wt2,
                               float* __restrict__ Wc1t, float* __restrict__ Wc2t) {
  int i = blockIdx.x * blockDim.x + threadIdx.x;
  if (i < 16384) {
    int f = i >> 7, k = i & 127;
    Wt1[k * 128 + f] = W1[i];
  } else if (i < 32768) {
    int j = i - 16384; int f = j >> 7, k = j & 127;
    Wt2[k * 128 + f] = W2[j];
  } else if (i < 81920) {
    int j = i - 32768; int f = j / 384, k = j % 384;
    Wc1t[k * 128 + f] = Wc1[j];
  } else if (i < 90112) {
    int j = i - 81920; int f = j >> 7, k = j & 127;
    Wc2t[k * 64 + f] = Wc2[j];
  }
}

// counts per-dst degree AND records each edge's arrival rank (makes scatter atomic-free)
__global__ void hist_kernel(const int* __restrict__ dst, int* __restrict__ cnt,
                            int* __restrict__ rank, int E) {
  int e = blockIdx.x * blockDim.x + threadIdx.x;
  if (e < E) rank[e] = atomicAdd(&cnt[dst[e]], 1);
}

// per-2048-chunk exclusive scan; bsum[b] = chunk total
__global__ void scan1_kernel(const int* __restrict__ cnt, int* __restrict__ rowptr,
                             int* __restrict__ bsum, int n) {
  __shared__ int smem[256];
  const int t = threadIdx.x;
  const int base = blockIdx.x * 2048 + t * 8;
  int v[8];
  int s = 0;
#pragma unroll
  for (int j = 0; j < 8; ++j) {
    int idx = base + j;
    v[j] = (idx < n) ? cnt[idx] : 0;
    s += v[j];
  }
  smem[t] = s;
  __syncthreads();
  for (int off = 1; off < 256; off <<= 1) {
    int add = (t >= off) ? smem[t - off] : 0;
    __syncthreads();
    smem[t] += add;
    __syncthreads();
  }
  int run = smem[t] - s;
  if (t == 255) bsum[blockIdx.x] = smem[255];
#pragma unroll
  for (int j = 0; j < 8; ++j) {
    int idx = base + j;
    if (idx < n) rowptr[idx] = run;
    run += v[j];
  }
}

// 64-lane shuffle scan (nchunk=49 fits)
__global__ void scan2_kernel(int* __restrict__ bsum, int nb) {
  const int t = threadIdx.x;
  if (nb <= 64) {
    const int orig = (t < nb) ? bsum[t] : 0;
    int v = orig;
#pragma unroll
    for (int off = 1; off < 64; off <<= 1) {
      int u = __shfl_up(v, off);
      if (t >= off) v += u;
    }
    if (t < nb) bsum[t] = v - orig;
  } else if (t == 0) {
    int run = 0;
    for (int i = 0; i < nb; ++i) { int v = bsum[i]; bsum[i] = run; run += v; }
  }
}

__global__ void scan3_kernel(int* __restrict__ rowptr, const int* __restrict__ bsum,
                             int n, int E) {
  int i = blockIdx.x * blockDim.x + threadIdx.x;
  if (i < n) rowptr[i] += bsum[i >> 11];
  if (i == 0) rowptr[n] = E;
}

// atomic-free scatter: pos = rowptr[dst] + rank (rank recorded in hist)
__global__ void scatter_kernel(const int* __restrict__ src, const int* __restrict__ dst,
                               const float* __restrict__ w, const int* __restrict__ rowptr,
                               const int* __restrict__ rank, int2* __restrict__ epack, int E) {
  int e = blockIdx.x * blockDim.x + threadIdx.x;
  if (e < E) {
    int pos = rowptr[dst[e]] + rank[e];
    epack[pos] = make_int2(src[e], __float_as_int(w[e]));
  }
}

// Stage 1: block's 32 rows = contiguous edge range, split into 8 equal laneset
// chunks. Each laneset walks its chunk in groups of 8: load 8 edge descriptors,
// issue 8 INDEPENDENT float4 row-gathers (8 in flight per stall), then consume,
// flushing the register accumulator to LDS (atomic) only at row transitions.
// Stage 2: finalize (1+eps)x + agg/deg. Stage 3: 32x128 @ 128x128 GEMM.
__launch_bounds__(256, 6)
__global__ void conv_kernel(const float* __restrict__ xin, float* __restrict__ xout,
                            const int* __restrict__ rowptr, const int2* __restrict__ epack,
                            const float* __restrict__ Wt,
                            const float* __restrict__ bias, const float* __restrict__ eps,
                            int epsidx, int dorelu, int zerorow0, int n) {
  __shared__ float xm[CONV_NPB * 128];
  __shared__ int rp_s[CONV_NPB + 1];
  const int t = threadIdx.x;
  const int nb = blockIdx.x * CONV_NPB;
  const float epsv = 1.0f + eps[epsidx];

  // zero accumulator tile + cache rowptr slice
#pragma unroll
  for (int i = 0; i < 4; ++i)
    *(float4*)&xm[(t + i * 256) * 4] = make_float4(0.f, 0.f, 0.f, 0.f);
  if (t <= CONV_NPB) {
    int node = nb + t;
    rp_s[t] = rowptr[node <= n ? node : n];
  }
  __syncthreads();

  // ---- stage 1: edge-balanced gather, 8-deep pipeline ----
  {
    const int L = t >> 5;         // laneset 0..7
    const int lane = t & 31;
    const int f0 = lane * 4;
    const int e0 = rp_s[0], eT = rp_s[CONV_NPB];
    const int total = eT - e0;
    const int chunk = (total + 7) >> 3;
    int j = e0 + L * chunk;
    const int j1 = min(j + chunk, eT);
    if (j < j1) {
      int r = 0;
      while (rp_s[r + 1] <= j) ++r;           // starting row of this chunk
      float ax = 0.f, ay = 0.f, az = 0.f, aw = 0.f;
      while (j < j1) {
        const int m = min(8, j1 - j);
        int2 p[8];
        float4 a[8];
#pragma unroll
        for (int i = 0; i < 8; ++i)
          if (i < m) p[i] = epack[j + i];
#pragma unroll
        for (int i = 0; i < 8; ++i)
          if (i < m) a[i] = *(const float4*)&xin[(size_t)p[i].x * 128 + f0];
#pragma unroll
        for (int i = 0; i < 8; ++i) {
          if (i < m) {
            if (j + i >= rp_s[r + 1]) {       // row transition: flush (laneset-uniform)
              float* dstp = &xm[r * 128 + f0];
              atomicAdd(dstp + 0, ax);
              atomicAdd(dstp + 1, ay);
              atomicAdd(dstp + 2, az);
              atomicAdd(dstp + 3, aw);
              ax = ay = az = aw = 0.f;
              do { ++r; } while (rp_s[r + 1] <= j + i);
            }
            const float wv = __int_as_float(p[i].y);
            ax += wv * a[i].x;
            ay += wv * a[i].y;
            az += wv * a[i].z;
            aw += wv * a[i].w;
          }
        }
        j += m;
      }
      float* dstp = &xm[r * 128 + f0];
      atomicAdd(dstp + 0, ax);
      atomicAdd(dstp + 1, ay);
      atomicAdd(dstp + 2, az);
      atomicAdd(dstp + 3, aw);
    }
  }
  __syncthreads();

  // ---- stage 2: finalize (1+eps)*x + agg/deg ----
  {
#pragma unroll
    for (int q = 0; q < 4; ++q) {
      const int task = t + q * 256;           // 32 rows x 32 fgroups = 1024
      const int r = task >> 5;
      const int f0 = (task & 31) * 4;
      const int node = nb + r;
      if (node < n) {
        const int d = rp_s[r + 1] - rp_s[r];
        const float rdeg = 1.0f / (float)(d > 1 ? d : 1);
        const float4 xv = *(const float4*)&xin[(size_t)node * 128 + f0];
        float4 m = *(const float4*)&xm[r * 128 + f0];
        m.x = epsv * xv.x + m.x * rdeg;
        m.y = epsv * xv.y + m.y * rdeg;
        m.z = epsv * xv.z + m.z * rdeg;
        m.w = epsv * xv.w + m.w * rdeg;
        *(float4*)&xm[r * 128 + f0] = m;
      }
    }
  }
  __syncthreads();

  // ---- stage 3: GEMM, thread tile = 4 rows x 4 features ----
  {
    const int fg = t & 31;
    const int rg = t >> 5;
    const int f0 = fg * 4;
    const int r0 = rg * 4;
    float4 acc[4];
#pragma unroll
    for (int r = 0; r < 4; ++r) acc[r] = make_float4(0.f, 0.f, 0.f, 0.f);
    for (int k = 0; k < 128; k += 4) {
      const float4 w0 = *(const float4*)&Wt[(k + 0) * 128 + f0];
      const float4 w1 = *(const float4*)&Wt[(k + 1) * 128 + f0];
      const float4 w2 = *(const float4*)&Wt[(k + 2) * 128 + f0];
      const float4 w3 = *(const float4*)&Wt[(k + 3) * 128 + f0];
#pragma unroll
      for (int r = 0; r < 4; ++r) {
        const float4 xv = *(const float4*)&xm[(r0 + r) * 128 + k];
        acc[r].x += xv.x * w0.x + xv.y * w1.x + xv.z * w2.x + xv.w * w3.x;
        acc[r].y += xv.x * w0.y + xv.y * w1.y + xv.z * w2.y + xv.w * w3.y;
        acc[r].z += xv.x * w0.z + xv.y * w1.z + xv.z * w2.z + xv.w * w3.z;
        acc[r].w += xv.x * w0.w + xv.y * w1.w + xv.z * w2.w + xv.w * w3.w;
      }
    }
    const float4 bv = *(const float4*)&bias[f0];
#pragma unroll
    for (int r = 0; r < 4; ++r) {
      const int node = nb + r0 + r;
      if (node < n) {
        float4 v;
        v.x = acc[r].x + bv.x;
        v.y = acc[r].y + bv.y;
        v.z = acc[r].z + bv.z;
        v.w = acc[r].w + bv.w;
        if (dorelu) {
          v.x = fmaxf(v.x, 0.f); v.y = fmaxf(v.y, 0.f);
          v.z = fmaxf(v.z, 0.f); v.w = fmaxf(v.w, 0.f);
        }
        if (zerorow0 && node == 0) { v.x = 0.f; v.y = 0.f; v.z = 0.f; v.w = 0.f; }
        *(float4*)&xout[(size_t)node * 128 + f0] = v;
      }
    }
  }
}

// One block (128 thr) per batch element: gather ing1/ing2/ctx into LDS, MLP 384->128->64->1.
__launch_bounds__(128, 4)
__global__ void final_kernel(const float* __restrict__ x2, const int* __restrict__ indices,
                             const float* __restrict__ Wc1t, const float* __restrict__ bc1,
                             const float* __restrict__ Wc2t, const float* __restrict__ bc2,
                             const float* __restrict__ Wc3, const float* __restrict__ bc3,
                             float* __restrict__ out) {
  __shared__ float ysm[384];
  __shared__ float h1s[128];
  const int b = blockIdx.x;
  const int t = threadIdx.x;
  const int* ind = indices + (size_t)b * 23;

  {
    const int i0 = ind[0];
    const int i1 = ind[1];
    ysm[t] = x2[(size_t)i0 * 128 + t];
    ysm[128 + t] = x2[(size_t)i1 * 128 + t];
    float cs = 0.f;
    int cc = 0;
#pragma unroll
    for (int j = 0; j < 20; ++j) {
      const int cj = ind[3 + j];
      cc += (cj > 0) ? 1 : 0;
      cs += x2[(size_t)cj * 128 + t];
    }
    ysm[256 + t] = cs / (float)(cc > 0 ? cc : 1);
  }
  __syncthreads();

  {
    float acc = bc1[t];
    for (int k = 0; k < 384; k += 4) {
      const float4 yv = *(const float4*)&ysm[k];
      acc += yv.x * Wc1t[(k + 0) * 128 + t];
      acc += yv.y * Wc1t[(k + 1) * 128 + t];
      acc += yv.z * Wc1t[(k + 2) * 128 + t];
      acc += yv.w * Wc1t[(k + 3) * 128 + t];
    }
    h1s[t] = fmaxf(acc, 0.f);
  }
  __syncthreads();

  if (t < 64) {
    float acc = bc2[t];
    for (int k = 0; k < 128; k += 4) {
      const float4 hv = *(const float4*)&h1s[k];
      acc += hv.x * Wc2t[(k + 0) * 64 + t];
      acc += hv.y * Wc2t[(k + 1) * 64 + t];
      acc += hv.z * Wc2t[(k + 2) * 64 + t];
      acc += hv.w * Wc2t[(k + 3) * 64 + t];
    }
    float v = fmaxf(acc, 0.f) * Wc3[t];
#pragma unroll
    for (int o = 32; o > 0; o >>= 1) v += __shfl_down(v, o);
    if (t == 0) out[b] = v + bc3[0];
  }
}

extern "C" void kernel_launch(void* const* d_in, const int* in_sizes, int n_in,
                              void* d_out, int out_size, void* d_ws, size_t ws_size,
                              hipStream_t stream) {
  const int* indices = (const int*)d_in[0];
  const int* src = (const int*)d_in[1];
  const int* dst = (const int*)d_in[2];
  const float* w = (const float*)d_in[3];
  const float* ndata = (const float*)d_in[4];
  const float* W1 = (const float*)d_in[5];
  const float* b1 = (const float*)d_in[6];
  const float* W2 = (const float*)d_in[7];
  const float* b2 = (const float*)d_in[8];
  const float* eps = (const float*)d_in[9];
  const float* Wc1 = (const float*)d_in[10];
  const float* bc1 = (const float*)d_in[11];
  const float* Wc2 = (const float*)d_in[12];
  const float* bc2 = (const float*)d_in[13];
  const float* Wc3 = (const float*)d_in[14];
  const float* bc3 = (const float*)d_in[15];
  float* out = (float*)d_out;

  const int E = in_sizes[1];
  const int N = in_sizes[4] / 128;
  const int B = in_sizes[0] / 23;

  char* ws = (char*)d_ws;
  size_t off = 0;
  auto alloc = [&](size_t bytes) -> char* {
    char* p = ws + off;
    off = (off + bytes + 255) & ~(size_t)255;
    return p;
  };
  int* cnt = (int*)alloc((size_t)N * 4);
  int* rowptr = (int*)alloc((size_t)(N + 1) * 4);
  int* rank = (int*)alloc((size_t)E * 4);
  int* bsum = (int*)alloc(256 * 4);
  int2* epack = (int2*)alloc((size_t)E * 8);
  float* x1 = (float*)alloc((size_t)N * 128 * 4);
  float* x2 = (float*)alloc((size_t)N * 128 * 4);
  float* Wt1 = (float*)alloc(16384 * 4);
  float* Wt2 = (float*)alloc(16384 * 4);
  float* Wc1t = (float*)alloc(49152 * 4);
  float* Wc2t = (float*)alloc(8192 * 4);

  hipMemsetAsync(cnt, 0, (size_t)N * 4, stream);

  prep_transpose<<<(90112 + 255) / 256, 256, 0, stream>>>(W1, W2, Wc1, Wc2, Wt1, Wt2, Wc1t, Wc2t);
  hist_kernel<<<(E + 255) / 256, 256, 0, stream>>>(dst, cnt, rank, E);
  const int nchunk = (N + 2047) / 2048;
  scan1_kernel<<<nchunk, 256, 0, stream>>>(cnt, rowptr, bsum, N);
  scan2_kernel<<<1, 64, 0, stream>>>(bsum, nchunk);
  scan3_kernel<<<(N + 255) / 256, 256, 0, stream>>>(rowptr, bsum, N, E);
  scatter_kernel<<<(E + 255) / 256, 256, 0, stream>>>(src, dst, w, rowptr, rank, epack, E);

  const int nconv = (N + CONV_NPB - 1) / CONV_NPB;
  conv_kernel<<<nconv, 256, 0, stream>>>(ndata, x1, rowptr, epack, Wt1, b1, eps, 0, 1, 0, N);
  conv_kernel<<<nconv, 256, 0, stream>>>(x1, x2, rowptr, epack, Wt2, b2, eps, 1, 0, 1, N);

  final_kernel<<<B, 128, 0, stream>>>(x2, indices, Wc1t, bc1, Wc2t, bc2, Wc3, bc3, out);
}